// Round 12
// baseline (114.220 us; speedup 1.0000x reference)
//
#include <hip/hip_runtime.h>

#define NNODES 4096
#define DIM 512
#define QKVD 1536
#define MAXE 96  // bucket capacity per dst row (Poisson(32): P(deg>96) ~ 1e-18)

typedef __bf16 bf16_t;
typedef bf16_t bf16x8 __attribute__((ext_vector_type(8)));
typedef bf16_t bf16x2 __attribute__((ext_vector_type(2)));
typedef float f32x4 __attribute__((ext_vector_type(4)));
typedef unsigned int uint;

__device__ __forceinline__ bf16x8 cvt8(float4 a, float4 b) {
  bf16x8 r;
  r[0] = (bf16_t)a.x; r[1] = (bf16_t)a.y; r[2] = (bf16_t)a.z; r[3] = (bf16_t)a.w;
  r[4] = (bf16_t)b.x; r[5] = (bf16_t)b.y; r[6] = (bf16_t)b.z; r[7] = (bf16_t)b.w;
  return r;
}

// ---------------- QKV GEMM (f32 inputs, cast-on-stage) + edge fill + Wo/W1 cast ----------------
// blocks [0,384): GEMM tiles; [384, 384+fillB): edge fill; [384+fillB, +512): Wo/W1 cast
__global__ __launch_bounds__(256) void qkv_fill_cast_k(const float* __restrict__ x,
                                                       const float* __restrict__ wqkv,
                                                       const float* __restrict__ bias,
                                                       bf16_t* __restrict__ Cout,
                                                       const int* __restrict__ ei,
                                                       uint* __restrict__ deg,
                                                       int* __restrict__ colv,
                                                       uint* __restrict__ eidv, int E,
                                                       const float* __restrict__ wo,
                                                       const float* __restrict__ w1,
                                                       bf16_t* __restrict__ wob,
                                                       bf16_t* __restrict__ w1b) {
  __shared__ bf16_t As[128][40];
  __shared__ bf16_t Bs[128][40];
  const int bid = blockIdx.x;
  const int t = threadIdx.x;
  const int fillB = (E + 255) / 256;

  if (bid >= 384) {
    int r = bid - 384;
    if (r < fillB) {  // ---- edge fill path ----
      int e = r * 256 + t;
      if (e < E) {
        int src = ei[e] & (NNODES - 1);
        int dst = ei[E + e] & (NNODES - 1);
        uint pos = atomicAdd(&deg[dst], 1u);
        if (pos < MAXE) {
          colv[dst * MAXE + pos] = src;
          eidv[dst * MAXE + pos] = (uint)e + 1u;  // 0 reserved for diagonal self-entry
        }
      }
    } else {  // ---- Wo/W1 cast path: 512 blocks x 256 thr x float4 ----
      int i = (r - fillB) * 256 + t;  // 0..131071
      const float* src;
      bf16_t* dst;
      int off;
      if (i < 65536) { src = wo; dst = wob; off = i; }
      else { src = w1; dst = w1b; off = i - 65536; }
      float4 v = ((const float4*)src)[off];
      dst[4 * off + 0] = (bf16_t)v.x;
      dst[4 * off + 1] = (bf16_t)v.y;
      dst[4 * off + 2] = (bf16_t)v.z;
      dst[4 * off + 3] = (bf16_t)v.w;
    }
    return;
  }

  // ---- GEMM path: tile 128x128, Nt=1536, K=512, f32->bf16 on stage ----
  const int lane = t & 63, w = t >> 6;
  const int wr = (w >> 1) * 64, wc = (w & 1) * 64;
  const int m0 = (bid / 12) * 128, n0 = (bid % 12) * 128;
  f32x4 acc[4][4] = {};
  const int r_ld = t >> 2;
  const int c_ld = (t & 3) * 8;

  for (int k0 = 0; k0 < 512; k0 += 32) {
#pragma unroll
    for (int seg = 0; seg < 2; ++seg) {
      int row = r_ld + seg * 64;
      const float* ap = x + (long)(m0 + row) * 512 + k0 + c_ld;
      const float* bp = wqkv + (long)(n0 + row) * 512 + k0 + c_ld;
      float4 a0 = *(const float4*)ap;
      float4 a1 = *(const float4*)(ap + 4);
      float4 b0 = *(const float4*)bp;
      float4 b1 = *(const float4*)(bp + 4);
      *(bf16x8*)&As[row][c_ld] = cvt8(a0, a1);
      *(bf16x8*)&Bs[row][c_ld] = cvt8(b0, b1);
    }
    __syncthreads();
    bf16x8 af[4], bfr[4];
    const int kg = (lane >> 4) * 8;
#pragma unroll
    for (int i = 0; i < 4; ++i) {
      af[i] = *(const bf16x8*)&As[wr + i * 16 + (lane & 15)][kg];
      bfr[i] = *(const bf16x8*)&Bs[wc + i * 16 + (lane & 15)][kg];
    }
#pragma unroll
    for (int i = 0; i < 4; ++i)
#pragma unroll
      for (int j = 0; j < 4; ++j)
        acc[i][j] = __builtin_amdgcn_mfma_f32_16x16x32_bf16(af[i], bfr[j], acc[i][j], 0, 0, 0);
    __syncthreads();
  }

  const int cr = (lane >> 4) * 4;
  const int cc = lane & 15;
#pragma unroll
  for (int i = 0; i < 4; ++i) {
#pragma unroll
    for (int j = 0; j < 4; ++j) {
      int n = n0 + wc + j * 16 + cc;
      float bv = bias[n];
#pragma unroll
      for (int r = 0; r < 4; ++r) {
        int m = m0 + wr + i * 16 + cr + r;
        Cout[(long)m * QKVD + n] = (bf16_t)(acc[i][j][r] + bv);
      }
    }
  }
}

// ---------------- bf16 MFMA GEMM: C = A @ B^T + bias, tile 128x64 (Wo/FFN) ----------------
template <bool OUT_BF16>
__global__ __launch_bounds__(256) void gemm_bt(const bf16_t* __restrict__ A,
                                               const bf16_t* __restrict__ B,
                                               const float* __restrict__ bias,
                                               void* __restrict__ Cout,
                                               int M, int Nt, int K) {
  __shared__ bf16_t As[128][40];
  __shared__ bf16_t Bs[64][40];
  const int t = threadIdx.x;
  const int lane = t & 63, w = t >> 6;
  const int wr = (w >> 1) * 64, wc = (w & 1) * 32;
  const int m0 = blockIdx.y * 128, n0 = blockIdx.x * 64;
  f32x4 acc[4][2] = {};
  const int r_ld = t >> 2;
  const int c_ld = (t & 3) * 8;

  for (int k0 = 0; k0 < K; k0 += 32) {
    *(int4*)&As[r_ld][c_ld] = *(const int4*)(A + (long)(m0 + r_ld) * K + k0 + c_ld);
    *(int4*)&As[r_ld + 64][c_ld] = *(const int4*)(A + (long)(m0 + r_ld + 64) * K + k0 + c_ld);
    *(int4*)&Bs[r_ld][c_ld] = *(const int4*)(B + (long)(n0 + r_ld) * K + k0 + c_ld);
    __syncthreads();
    bf16x8 af[4], bfr[2];
    const int kg = (lane >> 4) * 8;
#pragma unroll
    for (int i = 0; i < 4; ++i)
      af[i] = *(const bf16x8*)&As[wr + i * 16 + (lane & 15)][kg];
#pragma unroll
    for (int j = 0; j < 2; ++j)
      bfr[j] = *(const bf16x8*)&Bs[wc + j * 16 + (lane & 15)][kg];
#pragma unroll
    for (int i = 0; i < 4; ++i)
#pragma unroll
      for (int j = 0; j < 2; ++j)
        acc[i][j] = __builtin_amdgcn_mfma_f32_16x16x32_bf16(af[i], bfr[j], acc[i][j], 0, 0, 0);
    __syncthreads();
  }

  const int cr = (lane >> 4) * 4;
  const int cc = lane & 15;
#pragma unroll
  for (int i = 0; i < 4; ++i) {
#pragma unroll
    for (int j = 0; j < 2; ++j) {
      int n = n0 + wc + j * 16 + cc;
      float bv = bias[n];
#pragma unroll
      for (int r = 0; r < 4; ++r) {
        int m = m0 + wr + i * 16 + cr + r;
        float vv = acc[i][j][r] + bv;
        if (OUT_BF16)
          ((bf16_t*)Cout)[(long)m * Nt + n] = (bf16_t)vv;
        else
          ((float*)Cout)[(long)m * Nt + n] = vv;
      }
    }
  }
}

// ---------------- fused sparse attention (round-4 structure, 4-way unroll) ----------------
// one block (256 thr) per dst row; score/PV wave-parallel over entries
__global__ __launch_bounds__(256) void attn_fused_k(const bf16_t* __restrict__ qkv,
                                                    const float* __restrict__ ew,
                                                    const uint* __restrict__ deg,
                                                    const int* __restrict__ colv,
                                                    const uint* __restrict__ eidv,
                                                    bf16_t* __restrict__ outb) {
  __shared__ float scs[8][MAXE + 1];
  __shared__ int srcs[MAXE + 1];
  __shared__ uint eids[MAXE + 1];
  __shared__ int vld[MAXE + 1];
  __shared__ float invs_s[8];
  __shared__ float vacc[4][DIM];

  const int i = blockIdx.x;
  const int t = threadIdx.x;
  const int lane = t & 63, w = t >> 6;

  uint dg = deg[i];
  int L = (dg < (uint)MAXE) ? (int)dg : MAXE;
  int n = L + 1;

  if (t < L) {
    srcs[t] = colv[i * MAXE + t];
    eids[t] = eidv[i * MAXE + t];
  }
  if (t == L) { srcs[L] = i; eids[L] = 0u; }
  __syncthreads();

  // deterministic dedupe (last edge-id wins per src)
  if (t < n) {
    int sj = srcs[t];
    uint my = eids[t];
    int ok = 1;
    for (int j = 0; j < n; ++j)
      ok &= !((srcs[j] == sj) & (eids[j] > my));
    vld[t] = ok;
  }
  __syncthreads();

  // scores: wave per entry (stride 4), 4-way unrolled; lane = 16B chunk of K row
  const bf16x8 qv = *(const bf16x8*)(qkv + (long)i * QKVD + lane * 8);
  {
    int e = w;
    for (; e + 12 < n; e += 16) {
      const bf16x8 ka = *(const bf16x8*)(qkv + (long)srcs[e] * QKVD + DIM + lane * 8);
      const bf16x8 kb = *(const bf16x8*)(qkv + (long)srcs[e + 4] * QKVD + DIM + lane * 8);
      const bf16x8 kc = *(const bf16x8*)(qkv + (long)srcs[e + 8] * QKVD + DIM + lane * 8);
      const bf16x8 kd = *(const bf16x8*)(qkv + (long)srcs[e + 12] * QKVD + DIM + lane * 8);
      float d0 = 0.f, d1 = 0.f, d2 = 0.f, d3 = 0.f;
#pragma unroll
      for (int j = 0; j < 8; ++j) {
        float q = (float)qv[j];
        d0 += q * (float)ka[j];
        d1 += q * (float)kb[j];
        d2 += q * (float)kc[j];
        d3 += q * (float)kd[j];
      }
#pragma unroll
      for (int o = 1; o < 8; o <<= 1) {
        d0 += __shfl_xor(d0, o);
        d1 += __shfl_xor(d1, o);
        d2 += __shfl_xor(d2, o);
        d3 += __shfl_xor(d3, o);
      }
      if ((lane & 7) == 0) {
        int h = lane >> 3;
        scs[h][e] = vld[e] ? (d0 * 0.125f + ((eids[e] == 0u) ? 0.f : ew[eids[e] - 1u])) : -1e30f;
        scs[h][e + 4] = vld[e + 4] ? (d1 * 0.125f + ((eids[e + 4] == 0u) ? 0.f : ew[eids[e + 4] - 1u])) : -1e30f;
        scs[h][e + 8] = vld[e + 8] ? (d2 * 0.125f + ((eids[e + 8] == 0u) ? 0.f : ew[eids[e + 8] - 1u])) : -1e30f;
        scs[h][e + 12] = vld[e + 12] ? (d3 * 0.125f + ((eids[e + 12] == 0u) ? 0.f : ew[eids[e + 12] - 1u])) : -1e30f;
      }
    }
    for (; e < n; e += 4) {
      const bf16x8 ka = *(const bf16x8*)(qkv + (long)srcs[e] * QKVD + DIM + lane * 8);
      float d0 = 0.f;
#pragma unroll
      for (int j = 0; j < 8; ++j) d0 += (float)qv[j] * (float)ka[j];
#pragma unroll
      for (int o = 1; o < 8; o <<= 1) d0 += __shfl_xor(d0, o);
      if ((lane & 7) == 0) {
        int h = lane >> 3;
        scs[h][e] = vld[e] ? (d0 * 0.125f + ((eids[e] == 0u) ? 0.f : ew[eids[e] - 1u])) : -1e30f;
      }
    }
  }
  __syncthreads();

  // softmax: wave w handles heads 2w, 2w+1
#pragma unroll
  for (int hh = 0; hh < 2; ++hh) {
    int h = w * 2 + hh;
    float m = -1e30f;
    for (int e = lane; e < n; e += 64) m = fmaxf(m, scs[h][e]);
#pragma unroll
    for (int o = 32; o > 0; o >>= 1) m = fmaxf(m, __shfl_xor(m, o));
    float ps = 0.f;
    for (int e = lane; e < n; e += 64) {
      float ev = __expf(scs[h][e] - m);
      scs[h][e] = ev;  // invalid entries become exactly 0
      ps += ev;
    }
#pragma unroll
    for (int o = 32; o > 0; o >>= 1) ps += __shfl_xor(ps, o);
    if (lane == 0) invs_s[h] = 1.f / ps;
  }
  __syncthreads();

  // PV: wave-parallel over entries (stride 4), 4-way unrolled; lane = 8 dims
  const int hl = lane >> 3;
  float a8[8] = {0.f, 0.f, 0.f, 0.f, 0.f, 0.f, 0.f, 0.f};
  {
    int e = w;
    for (; e + 12 < n; e += 16) {
      const bf16x8 v0 = *(const bf16x8*)(qkv + (long)srcs[e] * QKVD + 2 * DIM + lane * 8);
      const bf16x8 v1 = *(const bf16x8*)(qkv + (long)srcs[e + 4] * QKVD + 2 * DIM + lane * 8);
      const bf16x8 v2 = *(const bf16x8*)(qkv + (long)srcs[e + 8] * QKVD + 2 * DIM + lane * 8);
      const bf16x8 v3 = *(const bf16x8*)(qkv + (long)srcs[e + 12] * QKVD + 2 * DIM + lane * 8);
      float p0 = scs[hl][e], p1 = scs[hl][e + 4], p2 = scs[hl][e + 8], p3 = scs[hl][e + 12];
#pragma unroll
      for (int j = 0; j < 8; ++j)
        a8[j] += p0 * (float)v0[j] + p1 * (float)v1[j] + p2 * (float)v2[j] + p3 * (float)v3[j];
    }
    for (; e < n; e += 4) {
      const bf16x8 v0 = *(const bf16x8*)(qkv + (long)srcs[e] * QKVD + 2 * DIM + lane * 8);
      float p0 = scs[hl][e];
#pragma unroll
      for (int j = 0; j < 8; ++j) a8[j] += p0 * (float)v0[j];
    }
  }
#pragma unroll
  for (int j = 0; j < 8; ++j) vacc[w][lane * 8 + j] = a8[j];
  __syncthreads();

  // final cross-wave reduce: thread t -> dims 2t, 2t+1
  {
    const int d0 = 2 * t;
    const int h = t >> 5;
    const float inv = invs_s[h];
    float s0 = vacc[0][d0] + vacc[1][d0] + vacc[2][d0] + vacc[3][d0];
    float s1 = vacc[0][d0 + 1] + vacc[1][d0 + 1] + vacc[2][d0 + 1] + vacc[3][d0 + 1];
    bf16x2 o2;
    o2[0] = (bf16_t)(s0 * inv);
    o2[1] = (bf16_t)(s1 * inv);
    *(bf16x2*)(outb + (long)i * DIM + d0) = o2;
  }
}

// ---------------- LayerNorm(a+b) ----------------
__global__ __launch_bounds__(64) void ln_k(const float* __restrict__ a,
                                           const float* __restrict__ b,
                                           const float* __restrict__ g,
                                           const float* __restrict__ beta,
                                           float* __restrict__ of,
                                           bf16_t* __restrict__ ob) {
  const int row = blockIdx.x;
  const int l = threadIdx.x;
  const float* pa = a + (long)row * DIM;
  const float* pb = b + (long)row * DIM;
  float v[8];
  float s = 0.f;
#pragma unroll
  for (int j = 0; j < 8; ++j) {
    int d = l + j * 64;
    v[j] = pa[d] + pb[d];
    s += v[j];
  }
#pragma unroll
  for (int o = 32; o > 0; o >>= 1) s += __shfl_xor(s, o);
  float mu = s * (1.f / 512.f);
  float q = 0.f;
#pragma unroll
  for (int j = 0; j < 8; ++j) {
    float dd = v[j] - mu;
    q += dd * dd;
  }
#pragma unroll
  for (int o = 32; o > 0; o >>= 1) q += __shfl_xor(q, o);
  float inv = rsqrtf(q * (1.f / 512.f) + 1e-5f);
#pragma unroll
  for (int j = 0; j < 8; ++j) {
    int d = l + j * 64;
    float y = (v[j] - mu) * inv * g[d] + beta[d];
    of[(long)row * DIM + d] = y;
    if (ob) ob[(long)row * DIM + d] = (bf16_t)y;
  }
}

// ---------------- launch ----------------
extern "C" void kernel_launch(void* const* d_in, const int* in_sizes, int n_in,
                              void* d_out, int out_size, void* d_ws, size_t ws_size,
                              hipStream_t stream) {
  const float* x = (const float*)d_in[0];
  const int* ei = (const int*)d_in[1];
  const float* ew = (const float*)d_in[2];
  const float* Wqkv = (const float*)d_in[3];
  const float* bqkv = (const float*)d_in[4];
  const float* Wo = (const float*)d_in[5];
  const float* bo = (const float*)d_in[6];
  const float* W1 = (const float*)d_in[7];
  const float* b1 = (const float*)d_in[8];
  const float* g1 = (const float*)d_in[9];
  const float* be1 = (const float*)d_in[10];
  const float* g2 = (const float*)d_in[11];
  const float* be2 = (const float*)d_in[12];
  float* out = (float*)d_out;
  const int E = in_sizes[1] / 2;

  char* ws = (char*)d_ws;
  bf16_t* qkvb = (bf16_t*)(ws + 0);           // 12,582,912 B
  bf16_t* Wob = (bf16_t*)(ws + 18350080);     // 524,288
  bf16_t* W1b = (bf16_t*)(ws + 18874368);     // 524,288
  bf16_t* outb = (bf16_t*)(ws + 19398656);    // 4,194,304
  float* h = (float*)(ws + 23592960);         // 8,388,608
  bf16_t* hb = (bf16_t*)(ws + 31981568);      // 4,194,304
  float* f = (float*)(ws + 36175872);         // 8,388,608 (end 44,564,480)
  // CSR buffers alias the h region (h is written only after attention is done)
  uint* deg = (uint*)(ws + 23592960);         // 16,384
  int* colv = (int*)(ws + 23609344);          // 1,572,864
  uint* eidv = (uint*)(ws + 25182208);        // 1,572,864 (end 26,755,072 < h end)
  float* attn_out = (float*)(ws + 0);         // alias over dead qkvb

  // 0: zero deg (16 KB)
  hipMemsetAsync(deg, 0, 16384, stream);

  // 1: QKV GEMM (f32 in, cast-on-stage) + edge fill + Wo/W1 cast, merged
  const int fillB = (E + 255) / 256;
  qkv_fill_cast_k<<<384 + fillB + 512, 256, 0, stream>>>(
      x, Wqkv, bqkv, qkvb, ei, deg, colv, eidv, E, Wo, W1, Wob, W1b);

  // 2: fused sparse attention (4-way unroll)
  attn_fused_k<<<NNODES, 256, 0, stream>>>(qkvb, ew, deg, colv, eidv, outb);

  // 3: output projection (f32 out, aliases qkvb space)
  gemm_bt<false><<<dim3(DIM / 64, NNODES / 128), 256, 0, stream>>>(
      outb, Wob, bo, (void*)attn_out, NNODES, DIM, DIM);

  // 4: LN1: h = LN(x + attn_out), also bf16 copy for FFN GEMM
  ln_k<<<NNODES, 64, 0, stream>>>(x, attn_out, g1, be1, h, hb);

  // 5: FFN: f = hb @ W1^T + b1
  gemm_bt<false><<<dim3(DIM / 64, NNODES / 128), 256, 0, stream>>>(
      hb, W1b, b1, (void*)f, NNODES, DIM, DIM);

  // 6: LN2 -> out
  ln_k<<<NNODES, 64, 0, stream>>>(h, f, g2, be2, out, nullptr);
}

// Round 13
// 106.888 us; speedup vs baseline: 1.0686x; 1.0686x over previous
//
#include <hip/hip_runtime.h>

#define NNODES 4096
#define DIM 512
#define QKVD 1536
#define MAXE 96  // bucket capacity per dst row (Poisson(32): P(deg>96) ~ 1e-18)

typedef __bf16 bf16_t;
typedef bf16_t bf16x8 __attribute__((ext_vector_type(8)));
typedef bf16_t bf16x2 __attribute__((ext_vector_type(2)));
typedef float f32x4 __attribute__((ext_vector_type(4)));
typedef unsigned int uint;

// ---------------- fused casts f32 -> bf16 (+ deg zero) ----------------
__global__ __launch_bounds__(256) void cast_all_k(const float* __restrict__ x,
                                                  const float* __restrict__ wqkv,
                                                  const float* __restrict__ wo,
                                                  const float* __restrict__ w1,
                                                  bf16_t* __restrict__ xb,
                                                  bf16_t* __restrict__ wqkvb,
                                                  bf16_t* __restrict__ wob,
                                                  bf16_t* __restrict__ w1b,
                                                  uint* __restrict__ deg) {
  int i = blockIdx.x * 256 + threadIdx.x;
  if (blockIdx.x < 16) deg[i] = 0u;  // 16*256 = 4096 rows
  const float* src;
  bf16_t* dst;
  int off;
  if (i < 524288) { src = x; dst = xb; off = i; }
  else if (i < 720896) { src = wqkv; dst = wqkvb; off = i - 524288; }
  else if (i < 786432) { src = wo; dst = wob; off = i - 720896; }
  else { src = w1; dst = w1b; off = i - 786432; }
  float4 v = ((const float4*)src)[off];
  dst[4 * off + 0] = (bf16_t)v.x;
  dst[4 * off + 1] = (bf16_t)v.y;
  dst[4 * off + 2] = (bf16_t)v.z;
  dst[4 * off + 3] = (bf16_t)v.w;
}

// ---------------- QKV GEMM (128x128, bf16 out) + bucket CSR fill, one dispatch ----------------
// blocks [0,384): GEMM tiles; blocks [384, 384+ceil(E/256)): edge fill
__global__ __launch_bounds__(256) void qkv_fill_k(const bf16_t* __restrict__ A,
                                                  const bf16_t* __restrict__ B,
                                                  const float* __restrict__ bias,
                                                  bf16_t* __restrict__ Cout,
                                                  const int* __restrict__ ei,
                                                  uint* __restrict__ deg,
                                                  int* __restrict__ colv,
                                                  uint* __restrict__ eidv, int E) {
  __shared__ bf16_t As[128][40];
  __shared__ bf16_t Bs[128][40];
  const int bid = blockIdx.x;
  const int t = threadIdx.x;

  if (bid >= 384) {  // ---- edge fill path ----
    int e = (bid - 384) * 256 + t;
    if (e < E) {
      int src = ei[e] & (NNODES - 1);
      int dst = ei[E + e] & (NNODES - 1);
      uint pos = atomicAdd(&deg[dst], 1u);
      if (pos < MAXE) {
        colv[dst * MAXE + pos] = src;
        eidv[dst * MAXE + pos] = (uint)e + 1u;  // 0 reserved for diagonal self-entry
      }
    }
    return;
  }

  // ---- GEMM path: tile 128x128, Nt=1536, K=512 ----
  const int lane = t & 63, w = t >> 6;
  const int wr = (w >> 1) * 64, wc = (w & 1) * 64;
  const int m0 = (bid / 12) * 128, n0 = (bid % 12) * 128;
  f32x4 acc[4][4] = {};
  const int r_ld = t >> 2;
  const int c_ld = (t & 3) * 8;

  for (int k0 = 0; k0 < 512; k0 += 32) {
#pragma unroll
    for (int seg = 0; seg < 2; ++seg) {
      int row = r_ld + seg * 64;
      *(int4*)&As[row][c_ld] = *(const int4*)(A + (long)(m0 + row) * 512 + k0 + c_ld);
      *(int4*)&Bs[row][c_ld] = *(const int4*)(B + (long)(n0 + row) * 512 + k0 + c_ld);
    }
    __syncthreads();
    bf16x8 af[4], bfr[4];
    const int kg = (lane >> 4) * 8;
#pragma unroll
    for (int i = 0; i < 4; ++i) {
      af[i] = *(const bf16x8*)&As[wr + i * 16 + (lane & 15)][kg];
      bfr[i] = *(const bf16x8*)&Bs[wc + i * 16 + (lane & 15)][kg];
    }
#pragma unroll
    for (int i = 0; i < 4; ++i)
#pragma unroll
      for (int j = 0; j < 4; ++j)
        acc[i][j] = __builtin_amdgcn_mfma_f32_16x16x32_bf16(af[i], bfr[j], acc[i][j], 0, 0, 0);
    __syncthreads();
  }

  const int cr = (lane >> 4) * 4;
  const int cc = lane & 15;
#pragma unroll
  for (int i = 0; i < 4; ++i) {
#pragma unroll
    for (int j = 0; j < 4; ++j) {
      int n = n0 + wc + j * 16 + cc;
      float bv = bias[n];
#pragma unroll
      for (int r = 0; r < 4; ++r) {
        int m = m0 + wr + i * 16 + cr + r;
        Cout[(long)m * QKVD + n] = (bf16_t)(acc[i][j][r] + bv);
      }
    }
  }
}

// ---------------- bf16 MFMA GEMM: C = A @ B^T + bias, tile 128x64 (Wo/FFN) ----------------
template <bool OUT_BF16>
__global__ __launch_bounds__(256) void gemm_bt(const bf16_t* __restrict__ A,
                                               const bf16_t* __restrict__ B,
                                               const float* __restrict__ bias,
                                               void* __restrict__ Cout,
                                               int M, int Nt, int K) {
  __shared__ bf16_t As[128][40];
  __shared__ bf16_t Bs[64][40];
  const int t = threadIdx.x;
  const int lane = t & 63, w = t >> 6;
  const int wr = (w >> 1) * 64, wc = (w & 1) * 32;
  const int m0 = blockIdx.y * 128, n0 = blockIdx.x * 64;
  f32x4 acc[4][2] = {};
  const int r_ld = t >> 2;
  const int c_ld = (t & 3) * 8;

  for (int k0 = 0; k0 < K; k0 += 32) {
    *(int4*)&As[r_ld][c_ld] = *(const int4*)(A + (long)(m0 + r_ld) * K + k0 + c_ld);
    *(int4*)&As[r_ld + 64][c_ld] = *(const int4*)(A + (long)(m0 + r_ld + 64) * K + k0 + c_ld);
    *(int4*)&Bs[r_ld][c_ld] = *(const int4*)(B + (long)(n0 + r_ld) * K + k0 + c_ld);
    __syncthreads();
    bf16x8 af[4], bfr[2];
    const int kg = (lane >> 4) * 8;
#pragma unroll
    for (int i = 0; i < 4; ++i)
      af[i] = *(const bf16x8*)&As[wr + i * 16 + (lane & 15)][kg];
#pragma unroll
    for (int j = 0; j < 2; ++j)
      bfr[j] = *(const bf16x8*)&Bs[wc + j * 16 + (lane & 15)][kg];
#pragma unroll
    for (int i = 0; i < 4; ++i)
#pragma unroll
      for (int j = 0; j < 2; ++j)
        acc[i][j] = __builtin_amdgcn_mfma_f32_16x16x32_bf16(af[i], bfr[j], acc[i][j], 0, 0, 0);
    __syncthreads();
  }

  const int cr = (lane >> 4) * 4;
  const int cc = lane & 15;
#pragma unroll
  for (int i = 0; i < 4; ++i) {
#pragma unroll
    for (int j = 0; j < 2; ++j) {
      int n = n0 + wc + j * 16 + cc;
      float bv = bias[n];
#pragma unroll
      for (int r = 0; r < 4; ++r) {
        int m = m0 + wr + i * 16 + cr + r;
        float vv = acc[i][j][r] + bv;
        if (OUT_BF16)
          ((bf16_t*)Cout)[(long)m * Nt + n] = (bf16_t)vv;
        else
          ((float*)Cout)[(long)m * Nt + n] = vv;
      }
    }
  }
}

// ---------------- fused sparse attention (round-4 measured-best) ----------------
// one block (256 thr) per dst row; score/PV wave-parallel over entries, 2-way unrolled
__global__ __launch_bounds__(256) void attn_fused_k(const bf16_t* __restrict__ qkv,
                                                    const float* __restrict__ ew,
                                                    const uint* __restrict__ deg,
                                                    const int* __restrict__ colv,
                                                    const uint* __restrict__ eidv,
                                                    bf16_t* __restrict__ outb) {
  __shared__ float scs[8][MAXE + 1];
  __shared__ int srcs[MAXE + 1];
  __shared__ uint eids[MAXE + 1];
  __shared__ int vld[MAXE + 1];
  __shared__ float invs_s[8];
  __shared__ float vacc[4][DIM];

  const int i = blockIdx.x;
  const int t = threadIdx.x;
  const int lane = t & 63, w = t >> 6;

  uint dg = deg[i];
  int L = (dg < (uint)MAXE) ? (int)dg : MAXE;
  int n = L + 1;

  if (t < L) {
    srcs[t] = colv[i * MAXE + t];
    eids[t] = eidv[i * MAXE + t];
  }
  if (t == L) { srcs[L] = i; eids[L] = 0u; }
  __syncthreads();

  // deterministic dedupe (last edge-id wins per src)
  if (t < n) {
    int sj = srcs[t];
    uint my = eids[t];
    int ok = 1;
    for (int j = 0; j < n; ++j)
      ok &= !((srcs[j] == sj) & (eids[j] > my));
    vld[t] = ok;
  }
  __syncthreads();

  // scores: wave per entry (stride 4), 2-way unrolled; lane = 16B chunk of K row
  const bf16x8 qv = *(const bf16x8*)(qkv + (long)i * QKVD + lane * 8);
  {
    int e = w;
    for (; e + 4 < n; e += 8) {
      int sa = srcs[e], sb = srcs[e + 4];
      const bf16x8 ka = *(const bf16x8*)(qkv + (long)sa * QKVD + DIM + lane * 8);
      const bf16x8 kb = *(const bf16x8*)(qkv + (long)sb * QKVD + DIM + lane * 8);
      float s0 = 0.f, s1 = 0.f;
#pragma unroll
      for (int j = 0; j < 8; ++j) {
        s0 += (float)qv[j] * (float)ka[j];
        s1 += (float)qv[j] * (float)kb[j];
      }
      s0 += __shfl_xor(s0, 1); s1 += __shfl_xor(s1, 1);
      s0 += __shfl_xor(s0, 2); s1 += __shfl_xor(s1, 2);
      s0 += __shfl_xor(s0, 4); s1 += __shfl_xor(s1, 4);
      if ((lane & 7) == 0) {
        int h = lane >> 3;
        float b0 = (eids[e] == 0u) ? 0.f : ew[eids[e] - 1u];
        float b1 = (eids[e + 4] == 0u) ? 0.f : ew[eids[e + 4] - 1u];
        scs[h][e] = vld[e] ? (s0 * 0.125f + b0) : -1e30f;
        scs[h][e + 4] = vld[e + 4] ? (s1 * 0.125f + b1) : -1e30f;
      }
    }
    if (e < n) {
      int sa = srcs[e];
      const bf16x8 ka = *(const bf16x8*)(qkv + (long)sa * QKVD + DIM + lane * 8);
      float s0 = 0.f;
#pragma unroll
      for (int j = 0; j < 8; ++j) s0 += (float)qv[j] * (float)ka[j];
      s0 += __shfl_xor(s0, 1);
      s0 += __shfl_xor(s0, 2);
      s0 += __shfl_xor(s0, 4);
      if ((lane & 7) == 0) {
        int h = lane >> 3;
        float b0 = (eids[e] == 0u) ? 0.f : ew[eids[e] - 1u];
        scs[h][e] = vld[e] ? (s0 * 0.125f + b0) : -1e30f;
      }
    }
  }
  __syncthreads();

  // softmax: wave w handles heads 2w, 2w+1
#pragma unroll
  for (int hh = 0; hh < 2; ++hh) {
    int h = w * 2 + hh;
    float m = -1e30f;
    for (int e = lane; e < n; e += 64) m = fmaxf(m, scs[h][e]);
#pragma unroll
    for (int o = 32; o > 0; o >>= 1) m = fmaxf(m, __shfl_xor(m, o));
    float ps = 0.f;
    for (int e = lane; e < n; e += 64) {
      float ev = __expf(scs[h][e] - m);
      scs[h][e] = ev;  // invalid entries become exactly 0
      ps += ev;
    }
#pragma unroll
    for (int o = 32; o > 0; o >>= 1) ps += __shfl_xor(ps, o);
    if (lane == 0) invs_s[h] = 1.f / ps;
  }
  __syncthreads();

  // PV: wave-parallel over entries (stride 4), 2-way unrolled; lane = 8 dims
  const int hl = lane >> 3;
  float a8[8] = {0.f, 0.f, 0.f, 0.f, 0.f, 0.f, 0.f, 0.f};
  {
    int e = w;
    for (; e + 4 < n; e += 8) {
      const bf16x8 v0 = *(const bf16x8*)(qkv + (long)srcs[e] * QKVD + 2 * DIM + lane * 8);
      const bf16x8 v1 = *(const bf16x8*)(qkv + (long)srcs[e + 4] * QKVD + 2 * DIM + lane * 8);
      float p0 = scs[hl][e], p1 = scs[hl][e + 4];
#pragma unroll
      for (int j = 0; j < 8; ++j) a8[j] += p0 * (float)v0[j] + p1 * (float)v1[j];
    }
    if (e < n) {
      const bf16x8 v0 = *(const bf16x8*)(qkv + (long)srcs[e] * QKVD + 2 * DIM + lane * 8);
      float p0 = scs[hl][e];
#pragma unroll
      for (int j = 0; j < 8; ++j) a8[j] += p0 * (float)v0[j];
    }
  }
#pragma unroll
  for (int j = 0; j < 8; ++j) vacc[w][lane * 8 + j] = a8[j];
  __syncthreads();

  // final cross-wave reduce: thread t -> dims 2t, 2t+1
  {
    const int d0 = 2 * t;
    const int h = t >> 5;
    const float inv = invs_s[h];
    float s0 = vacc[0][d0] + vacc[1][d0] + vacc[2][d0] + vacc[3][d0];
    float s1 = vacc[0][d0 + 1] + vacc[1][d0 + 1] + vacc[2][d0 + 1] + vacc[3][d0 + 1];
    bf16x2 o2;
    o2[0] = (bf16_t)(s0 * inv);
    o2[1] = (bf16_t)(s1 * inv);
    *(bf16x2*)(outb + (long)i * DIM + d0) = o2;
  }
}

// ---------------- LayerNorm(a+b) ----------------
__global__ __launch_bounds__(64) void ln_k(const float* __restrict__ a,
                                           const float* __restrict__ b,
                                           const float* __restrict__ g,
                                           const float* __restrict__ beta,
                                           float* __restrict__ of,
                                           bf16_t* __restrict__ ob) {
  const int row = blockIdx.x;
  const int l = threadIdx.x;
  const float* pa = a + (long)row * DIM;
  const float* pb = b + (long)row * DIM;
  float v[8];
  float s = 0.f;
#pragma unroll
  for (int j = 0; j < 8; ++j) {
    int d = l + j * 64;
    v[j] = pa[d] + pb[d];
    s += v[j];
  }
#pragma unroll
  for (int o = 32; o > 0; o >>= 1) s += __shfl_xor(s, o);
  float mu = s * (1.f / 512.f);
  float q = 0.f;
#pragma unroll
  for (int j = 0; j < 8; ++j) {
    float dd = v[j] - mu;
    q += dd * dd;
  }
#pragma unroll
  for (int o = 32; o > 0; o >>= 1) q += __shfl_xor(q, o);
  float inv = rsqrtf(q * (1.f / 512.f) + 1e-5f);
#pragma unroll
  for (int j = 0; j < 8; ++j) {
    int d = l + j * 64;
    float y = (v[j] - mu) * inv * g[d] + beta[d];
    of[(long)row * DIM + d] = y;
    if (ob) ob[(long)row * DIM + d] = (bf16_t)y;
  }
}

// ---------------- launch ----------------
extern "C" void kernel_launch(void* const* d_in, const int* in_sizes, int n_in,
                              void* d_out, int out_size, void* d_ws, size_t ws_size,
                              hipStream_t stream) {
  const float* x = (const float*)d_in[0];
  const int* ei = (const int*)d_in[1];
  const float* ew = (const float*)d_in[2];
  const float* Wqkv = (const float*)d_in[3];
  const float* bqkv = (const float*)d_in[4];
  const float* Wo = (const float*)d_in[5];
  const float* bo = (const float*)d_in[6];
  const float* W1 = (const float*)d_in[7];
  const float* b1 = (const float*)d_in[8];
  const float* g1 = (const float*)d_in[9];
  const float* be1 = (const float*)d_in[10];
  const float* g2 = (const float*)d_in[11];
  const float* be2 = (const float*)d_in[12];
  float* out = (float*)d_out;
  const int E = in_sizes[1] / 2;

  char* ws = (char*)d_ws;
  bf16_t* qkvb = (bf16_t*)(ws + 0);           // 12,582,912 B
  bf16_t* xb = (bf16_t*)(ws + 12582912);      // 4,194,304
  bf16_t* Wqkvb = (bf16_t*)(ws + 16777216);   // 1,572,864
  bf16_t* Wob = (bf16_t*)(ws + 18350080);     // 524,288
  bf16_t* W1b = (bf16_t*)(ws + 18874368);     // 524,288
  bf16_t* outb = (bf16_t*)(ws + 19398656);    // 4,194,304
  float* h = (float*)(ws + 23592960);         // 8,388,608
  bf16_t* hb = (bf16_t*)(ws + 31981568);      // 4,194,304
  float* f = (float*)(ws + 36175872);         // 8,388,608 (end 44,564,480)
  // CSR buffers alias the h region (h is written only after attention is done)
  uint* deg = (uint*)(ws + 23592960);         // 16,384
  int* colv = (int*)(ws + 23609344);          // 1,572,864
  uint* eidv = (uint*)(ws + 25182208);        // 1,572,864 (end 26,755,072 < h end)
  float* attn_out = (float*)(ws + 0);         // alias over dead qkvb

  // 1: casts + deg zero
  cast_all_k<<<3328, 256, 0, stream>>>(x, Wqkv, Wo, W1, xb, Wqkvb, Wob, W1b, deg);

  // 2: QKV GEMM (128x128) + edge fill, merged
  qkv_fill_k<<<384 + (E + 255) / 256, 256, 0, stream>>>(
      xb, Wqkvb, bqkv, qkvb, ei, deg, colv, eidv, E);

  // 3: fused sparse attention (round-4 structure, measured best)
  attn_fused_k<<<NNODES, 256, 0, stream>>>(qkvb, ew, deg, colv, eidv, outb);

  // 4: output projection (f32 out, aliases qkvb space)
  gemm_bt<false><<<dim3(DIM / 64, NNODES / 128), 256, 0, stream>>>(
      outb, Wob, bo, (void*)attn_out, NNODES, DIM, DIM);

  // 5: LN1: h = LN(x + attn_out), also bf16 copy for FFN GEMM
  ln_k<<<NNODES, 64, 0, stream>>>(x, attn_out, g1, be1, h, hb);

  // 6: FFN: f = hb @ W1^T + b1
  gemm_bt<false><<<dim3(DIM / 64, NNODES / 128), 256, 0, stream>>>(
      hb, W1b, b1, (void*)f, NNODES, DIM, DIM);

  // 7: LN2 -> out
  ln_k<<<NNODES, 64, 0, stream>>>(h, f, g2, be2, out, nullptr);
}